// Round 13
// baseline (157.497 us; speedup 1.0000x reference)
//
#include <hip/hip_runtime.h>
#include <cstddef>
#include <cstdint>

#define NTOK 4096
#define NB_  8

// 0.25 (=1/sqrt(Cq)) * log2(e): folded into q so flash can use raw exp2.
#define QSCALE 0.36067376022224085f

typedef float f32x4  __attribute__((ext_vector_type(4)));
typedef float f32x16 __attribute__((ext_vector_type(16)));
typedef short s16x8  __attribute__((ext_vector_type(8)));

#if __has_builtin(__builtin_amdgcn_exp2f)
#define EXP2F(x) __builtin_amdgcn_exp2f(x)
#else
#define EXP2F(x) exp2f(x)
#endif

static __device__ __forceinline__ unsigned short f2bf(float f) {
    unsigned u = __float_as_uint(f);
    unsigned r = (u + 0x7FFFu + ((u >> 16) & 1u)) >> 16;
    return (unsigned short)r;
}

// 2 f32 -> packed bf16 pair (low half = a), RNE.
static __device__ __forceinline__ unsigned cvtpkbf(float a, float b) {
    unsigned r;
    asm("v_cvt_pk_bf16_f32 %0, %1, %2" : "=v"(r) : "v"(a), "v"(b));
    return r;
}

// v_permlane32_swap_b32: ret.x = [a(lanes0-31) | b(lanes0-31)],
//                        ret.y = [a(lanes32-63) | b(lanes32-63)].
static __device__ __forceinline__ uint2 plswap32(unsigned a, unsigned b) {
#if __has_builtin(__builtin_amdgcn_permlane32_swap)
    auto r = __builtin_amdgcn_permlane32_swap((int)a, (int)b, false, false);
    return make_uint2((unsigned)r[0], (unsigned)r[1]);
#else
    const int xa = (((int)threadIdx.x & 63) ^ 32) << 2;
    const unsigned pa = (unsigned)__builtin_amdgcn_ds_bpermute(xa, (int)a);
    const unsigned pb = (unsigned)__builtin_amdgcn_ds_bpermute(xa, (int)b);
    const bool hi = (threadIdx.x & 32) != 0;
    return make_uint2(hi ? pb : a, hi ? b : pa);
#endif
}

// lane^16 exchange (within each 32-lane half): ds_swizzle BitMode xor=16
static __device__ __forceinline__ unsigned swz16(unsigned v) {
    return (unsigned)__builtin_amdgcn_ds_swizzle((int)v, 0x401F);
}

// ---------------- P0: weights fp32 -> bf16 ----------------
__global__ __launch_bounds__(256) void wcvt_kernel(
    const float* __restrict__ Wq, const float* __restrict__ Wk, const float* __restrict__ Wv,
    unsigned short* __restrict__ wvb, unsigned short* __restrict__ wqb,
    unsigned short* __restrict__ wkb)
{
    int i = blockIdx.x * 256 + threadIdx.x;  // 0..20479
    if (i < 16384)      wvb[i]         = f2bf(Wv[i]);
    else if (i < 18432) wqb[i - 16384] = f2bf(Wq[i - 16384]);
    else                wkb[i - 18432] = f2bf(Wk[i - 18432]);
}

// ---------------- P1: fused transpose + projections (r8 config, best measured) ----
// Flat grid 512 blocks; b = blk & 7 pins each batch to one XCD. V written in
// flash's fragment-major layout: v3[b][jt=j>>6][s=(j>>4)&3][h=(j>>3)&1][c][e=j&7].
// Dense 16B V-stores via lane^16 ds_swizzle pairing (r7-verified).
__global__ __launch_bounds__(256) void proj_kernel(
    const float* __restrict__ x,
    const unsigned short* __restrict__ wvb, const unsigned short* __restrict__ wqb,
    const unsigned short* __restrict__ wkb,
    const float* __restrict__ bq, const float* __restrict__ bk, const float* __restrict__ bv,
    unsigned short* __restrict__ qb, unsigned short* __restrict__ kb,
    unsigned short* __restrict__ vt)
{
    __shared__ float lt[128][68];   // [c][n0..63], padded rows (16B-aligned stride)
    const int t = threadIdx.x;
    const int w = t >> 6, lane = t & 63;
    const int c16 = lane & 15, g16 = lane >> 4;
    const int b  = blockIdx.x & 7;
    const int n0 = (blockIdx.x >> 3) * 64;

    // stage x tile: 128 rows x 64 floats
    {
        const int n4 = t & 15;
#pragma unroll
        for (int pass = 0; pass < 8; ++pass) {
            const int c = (t >> 4) + 16 * pass;
            const float4 val = ((const float4*)(x + ((size_t)b * 128 + c) * NTOK + n0))[n4];
            *(float4*)&lt[c][n4 * 4] = val;
        }
    }
    __syncthreads();

    // xf fragments for this wave's 16 tokens (token = n0 + 16w + c16)
    const int nl = 16 * w + c16;
    s16x8 xf[4];
#pragma unroll
    for (int kc = 0; kc < 4; ++kc) {
        unsigned rr[8];
#pragma unroll
        for (int i = 0; i < 8; ++i) {
            const unsigned u = __float_as_uint(lt[32 * kc + 8 * g16 + i][nl]);
            rr[i] = u + 0x7FFFu + ((u >> 16) & 1u);
        }
        union { s16x8 v; unsigned u[4]; } cvt;
#pragma unroll
        for (int d = 0; d < 4; ++d)
            cvt.u[d] = __builtin_amdgcn_perm(rr[2 * d + 1], rr[2 * d], 0x07060302u);
        xf[kc] = cvt.v;
    }

    // ---- V = Wv * X  (fragment-major, dense 16B stores) ----
    unsigned short* vwp16 = vt + (size_t)b * (NTOK * 128) +
                            (size_t)(((n0 >> 6) * 8) + 2 * w + (g16 >> 1)) * 1024;
    const bool oddg = (g16 & 1) != 0;
#pragma unroll
    for (int mp = 0; mp < 4; ++mp) {
        f32x4 accA = {0.f, 0.f, 0.f, 0.f}, accB = {0.f, 0.f, 0.f, 0.f};
#pragma unroll
        for (int kc = 0; kc < 4; ++kc) {
            const s16x8 wfA = *(const s16x8*)(wvb + (size_t)(32 * mp      + c16) * 128 + 32 * kc + 8 * g16);
            const s16x8 wfB = *(const s16x8*)(wvb + (size_t)(32 * mp + 16 + c16) * 128 + 32 * kc + 8 * g16);
            accA = __builtin_amdgcn_mfma_f32_16x16x32_bf16(xf[kc], wfA, accA, 0, 0, 0);
            accB = __builtin_amdgcn_mfma_f32_16x16x32_bf16(xf[kc], wfB, accB, 0, 0, 0);
        }
        const float bvA = bv[32 * mp + c16], bvB = bv[32 * mp + 16 + c16];
        uint2 A, B;
        A.x = cvtpkbf(accA[0] + bvA, accA[1] + bvA);
        A.y = cvtpkbf(accA[2] + bvA, accA[3] + bvA);
        B.x = cvtpkbf(accB[0] + bvB, accB[1] + bvB);
        B.y = cvtpkbf(accB[2] + bvB, accB[3] + bvB);
        // exchange with lane^16: even lane keeps channel A row, odd keeps B row.
        const unsigned s0 = swz16(oddg ? A.x : B.x);
        const unsigned s1 = swz16(oddg ? A.y : B.y);
        uint4 W;
        W.x = oddg ? s0 : A.x;
        W.y = oddg ? s1 : A.y;
        W.z = oddg ? B.x : s0;
        W.w = oddg ? B.y : s1;
        const int crow = 32 * mp + (oddg ? 16 : 0) + c16;
        *(uint4*)(vwp16 + (size_t)crow * 8) = W;
    }
    // ---- Q, K ----
    f32x4 aq = {0.f, 0.f, 0.f, 0.f}, ak = {0.f, 0.f, 0.f, 0.f};
#pragma unroll
    for (int kc = 0; kc < 4; ++kc) {
        const s16x8 wqf = *(const s16x8*)(wqb + (size_t)c16 * 128 + 32 * kc + 8 * g16);
        const s16x8 wkf = *(const s16x8*)(wkb + (size_t)c16 * 128 + 32 * kc + 8 * g16);
        aq = __builtin_amdgcn_mfma_f32_16x16x32_bf16(wqf, xf[kc], aq, 0, 0, 0);
        ak = __builtin_amdgcn_mfma_f32_16x16x32_bf16(wkf, xf[kc], ak, 0, 0, 0);
    }
    const float4 bq4 = *(const float4*)(bq + 4 * g16);
    const float4 bk4 = *(const float4*)(bk + 4 * g16);
    const int n = n0 + 16 * w + c16;
    uint2 pq, pkk;
    pq.x  = cvtpkbf(QSCALE * (aq[0] + bq4.x), QSCALE * (aq[1] + bq4.y));
    pq.y  = cvtpkbf(QSCALE * (aq[2] + bq4.z), QSCALE * (aq[3] + bq4.w));
    pkk.x = cvtpkbf(ak[0] + bk4.x, ak[1] + bk4.y);
    pkk.y = cvtpkbf(ak[2] + bk4.z, ak[3] + bk4.w);
    *(uint2*)(qb + ((size_t)b * NTOK + n) * 16 + 4 * g16) = pq;
    *(uint2*)(kb + ((size_t)b * NTOK + n) * 16 + 4 * g16) = pkk;
}

// ---------------- P2: flash attention, staggered-wave register pipeline ------
// Grid 1024 blocks (4/CU): b = blk & 7 (XCD-pinned batch), m-tile = blk>>3
// (32 q rows). 4 waves = (jw 0..1) x (cv 0..1). No LDS/barriers in the loop.
//
// r12 lesson: the forced 2-stage pipeline took (VGPR 44->64) but only moved
// 68.5->66.6. Budget audit across ALL seven structures: per-CU L1-fill (~27us)
// + trans (~27us) + VALU (~6us) + MFMA (~4us) = 64us with NO overlap == every
// measured time. Mechanism: WAVE CONVOY - identical waves start aligned and
// every shared-pipe queue (trans burst, load burst) re-aligns them, so all
// waves hit the same pipe simultaneously while other pipes idle. No barrier
// needed to maintain lockstep; the queues do it.
// Fix: stagger wave phases. Wave w starts its j-loop at tile (w*16), iterating
// (jt + w*16) & 63 - semantically identical (O/l are reorder-safe sums), but
// concurrent waves are 16 tiles out of phase: one wave's exp burst overlaps
// another's loads and a third's MFMAs.
__global__ __launch_bounds__(256, 4) void flash_kernel(
    const unsigned short* __restrict__ qb, const unsigned short* __restrict__ kb,
    const unsigned short* __restrict__ vt, const float* __restrict__ x,
    const float* __restrict__ gamma, float* __restrict__ out)
{
    // cmb float[32][128] @0 (16384B); lb 4*32 floats @16384
    __shared__ __align__(16) unsigned char smem[16896];

    const int t = threadIdx.x;
    const int w = t >> 6, lane = t & 63;
    const int m31 = lane & 31, h = lane >> 5;
    const int cv = w & 1, jw = w >> 1;
    const int b  = blockIdx.x & 7;
    const int m0 = (blockIdx.x >> 3) * 32;
    const int phase = w * 16;   // convoy-breaking per-wave rotation

    // per-wave global bases (dense 1KB per wave-load)
    const unsigned short* vp = vt + (size_t)b * (NTOK * 128) +
                               (2 * jw) * 2048 + h * 1024 + (2 * cv) * 256 + m31 * 8;
    const unsigned short* kp = kb + (size_t)b * (NTOK * 16) +
                               (size_t)(32 * jw + m31) * 16 + 8 * h;

    // Q B-frag: B[k=ch 8h+e][n=m31]; scale (incl. log2e) pre-folded into qb.
    const s16x8 qf = *(const s16x8*)(qb + ((size_t)b * NTOK + m0 + m31) * 16 + 8 * h);

    f32x16 O[2];   // 32 loop-carried acc regs (ct = 2cv + ci), partial over half jw
#pragma unroll
    for (int ci = 0; ci < 2; ++ci)
#pragma unroll
        for (int r = 0; r < 16; ++r) O[ci][r] = 0.f;
    float la0 = 0.f, la1 = 0.f, la2 = 0.f, la3 = 0.f;

    s16x8 kA, a00, a01, a10, a11;   // operand set A
    s16x8 kB, b00, b01, b10, b11;   // operand set B

#define LOADSET(K, V00, V01, V10, V11, jn) do {                       \
        const unsigned short* kpn_ = kp + (size_t)(jn) * 1024;        \
        const unsigned short* vpn_ = vp + (size_t)(jn) * 8192;        \
        K   = *(const s16x8*)kpn_;                                    \
        V00 = *(const s16x8*)(vpn_);                                  \
        V01 = *(const s16x8*)(vpn_ + 256);                            \
        V10 = *(const s16x8*)(vpn_ + 2048);                           \
        V11 = *(const s16x8*)(vpn_ + 2304);                           \
    } while (0)

#define COMPUTE(K, V00, V01, V10, V11) do {                                         \
        f32x16 sd_;                                                                 \
        _Pragma("unroll") for (int r_ = 0; r_ < 16; ++r_) sd_[r_] = 0.f;            \
        sd_ = __builtin_amdgcn_mfma_f32_32x32x16_bf16(K, qf, sd_, 0, 0, 0);         \
        uint2 pk_[4];                                                               \
        _Pragma("unroll") for (int q_ = 0; q_ < 4; ++q_) {                          \
            const float e0_ = EXP2F(sd_[4 * q_ + 0]);                               \
            const float e1_ = EXP2F(sd_[4 * q_ + 1]);                               \
            const float e2_ = EXP2F(sd_[4 * q_ + 2]);                               \
            const float e3_ = EXP2F(sd_[4 * q_ + 3]);                               \
            la0 += e0_; la1 += e1_; la2 += e2_; la3 += e3_;                         \
            pk_[q_].x = cvtpkbf(e0_, e1_);                                          \
            pk_[q_].y = cvtpkbf(e2_, e3_);                                          \
        }                                                                           \
        s16x8 pf0_, pf1_;                                                           \
        {                                                                           \
            const uint2 rx_ = plswap32(pk_[0].x, pk_[1].x);                         \
            const uint2 ry_ = plswap32(pk_[0].y, pk_[1].y);                         \
            union { s16x8 v; unsigned u[4]; } U_;                                   \
            U_.u[0] = rx_.x; U_.u[1] = ry_.x; U_.u[2] = rx_.y; U_.u[3] = ry_.y;     \
            pf0_ = U_.v;                                                            \
        }                                                                           \
        {                                                                           \
            const uint2 rx_ = plswap32(pk_[2].x, pk_[3].x);                         \
            const uint2 ry_ = plswap32(pk_[2].y, pk_[3].y);                         \
            union { s16x8 v; unsigned u[4]; } U_;                                   \
            U_.u[0] = rx_.x; U_.u[1] = ry_.x; U_.u[2] = rx_.y; U_.u[3] = ry_.y;     \
            pf1_ = U_.v;                                                            \
        }                                                                           \
        O[0] = __builtin_amdgcn_mfma_f32_32x32x16_bf16(V00, pf0_, O[0], 0, 0, 0);   \
        O[1] = __builtin_amdgcn_mfma_f32_32x32x16_bf16(V01, pf0_, O[1], 0, 0, 0);   \
        O[0] = __builtin_amdgcn_mfma_f32_32x32x16_bf16(V10, pf1_, O[0], 0, 0, 0);   \
        O[1] = __builtin_amdgcn_mfma_f32_32x32x16_bf16(V11, pf1_, O[1], 0, 0, 0);   \
    } while (0)

    LOADSET(kA, a00, a01, a10, a11, phase & 63);
    LOADSET(kB, b00, b01, b10, b11, (phase + 1) & 63);

#pragma unroll 1
    for (int jt = 0; jt < 64; jt += 2) {
        // stage A: compute tile (jt+phase)&63 from regs loaded one stage ago
        COMPUTE(kA, a00, a01, a10, a11);
        LOADSET(kA, a00, a01, a10, a11, (jt + 2 + phase) & 63);
        __builtin_amdgcn_sched_barrier(0);   // pin A-loads above B-compute
        // stage B: compute tile (jt+1+phase)&63
        COMPUTE(kB, b00, b01, b10, b11);
        LOADSET(kB, b00, b01, b10, b11, (jt + 3 + phase) & 63);
        __builtin_amdgcn_sched_barrier(0);   // pin B-loads above next A-compute
    }
#undef LOADSET
#undef COMPUTE

    // own-half l (h-lanes hold disjoint j subsets of the half)
    float l_acc = (la0 + la1) + (la2 + la3);
    l_acc += __shfl_xor(l_acc, 32);

    // l across jw partner (w^2). (cv partners duplicate softmax -> same la.)
    float* cmb = (float*)smem;             // [32][128] floats
    float* lb  = (float*)(smem + 16384);   // [4][32]
    if (lane < 32) lb[w * 32 + m31] = l_acc;
    __syncthreads();
    const float l_tot = l_acc + lb[(w ^ 2) * 32 + m31];

    // O combine across jw: jw=1 publishes, jw=0 adds and stores.
    if (jw == 1) {
#pragma unroll
        for (int ci = 0; ci < 2; ++ci)
#pragma unroll
            for (int r = 0; r < 16; ++r)
                cmb[(ci * 16 + r) * 128 + cv * 64 + lane] = O[ci][r];
    }
    __syncthreads();
    if (jw == 0) {
        const float linv = 1.f / l_tot;
        const float g = gamma[0];
#pragma unroll
        for (int ci = 0; ci < 2; ++ci) {
            const int ct = 2 * cv + ci;
#pragma unroll
            for (int r = 0; r < 16; ++r) {
                const float ov = O[ci][r] + cmb[(ci * 16 + r) * 128 + cv * 64 + lane];
                const int c = 32 * ct + (r & 3) + 8 * (r >> 2) + 4 * h;
                const size_t idx = ((size_t)b * 128 + c) * NTOK + m0 + m31;
                out[idx] = fmaf(g, ov * linv, x[idx]);
            }
        }
    }
}

extern "C" void kernel_launch(void* const* d_in, const int* in_sizes, int n_in,
                              void* d_out, int out_size, void* d_ws, size_t ws_size,
                              hipStream_t stream)
{
    const float* x     = (const float*)d_in[0];
    const float* Wq    = (const float*)d_in[1];
    const float* bq    = (const float*)d_in[2];
    const float* Wk    = (const float*)d_in[3];
    const float* bk    = (const float*)d_in[4];
    const float* Wv    = (const float*)d_in[5];
    const float* bv    = (const float*)d_in[6];
    const float* gamma = (const float*)d_in[7];
    float* out = (float*)d_out;

    // workspace (bf16 elements)
    unsigned short* qb  = (unsigned short*)d_ws;                 // 8*4096*16
    unsigned short* kb  = qb  + (size_t)NB_ * NTOK * 16;
    unsigned short* vt  = kb  + (size_t)NB_ * NTOK * 16;         // 8*128*4096 (fragment-major)
    unsigned short* wvb = vt  + (size_t)NB_ * 128 * NTOK;        // 128*128
    unsigned short* wqb = wvb + 16384;                           // 16*128
    unsigned short* wkb = wqb + 2048;

    wcvt_kernel<<<80, 256, 0, stream>>>(Wq, Wk, Wv, wvb, wqb, wkb);
    proj_kernel<<<512, 256, 0, stream>>>(x, wvb, wqb, wkb, bq, bk, bv, qb, kb, vt);
    flash_kernel<<<1024, 256, 0, stream>>>(qb, kb, vt, x, gamma, out);
}

// Round 14
// 147.316 us; speedup vs baseline: 1.0691x; 1.0691x over previous
//
#include <hip/hip_runtime.h>
#include <cstddef>
#include <cstdint>

#define NTOK 4096
#define NB_  8

// 0.25 (=1/sqrt(Cq)) * log2(e): folded into q so flash can use raw exp2.
#define QSCALE 0.36067376022224085f

typedef float f32x4  __attribute__((ext_vector_type(4)));
typedef float f32x16 __attribute__((ext_vector_type(16)));
typedef short s16x8  __attribute__((ext_vector_type(8)));

#if __has_builtin(__builtin_amdgcn_exp2f)
#define EXP2F(x) __builtin_amdgcn_exp2f(x)
#else
#define EXP2F(x) exp2f(x)
#endif

static __device__ __forceinline__ unsigned short f2bf(float f) {
    unsigned u = __float_as_uint(f);
    unsigned r = (u + 0x7FFFu + ((u >> 16) & 1u)) >> 16;
    return (unsigned short)r;
}

// 2 f32 -> packed bf16 pair (low half = a), RNE.
static __device__ __forceinline__ unsigned cvtpkbf(float a, float b) {
    unsigned r;
    asm("v_cvt_pk_bf16_f32 %0, %1, %2" : "=v"(r) : "v"(a), "v"(b));
    return r;
}

// v_permlane32_swap_b32: ret.x = [a(lanes0-31) | b(lanes0-31)],
//                        ret.y = [a(lanes32-63) | b(lanes32-63)].
static __device__ __forceinline__ uint2 plswap32(unsigned a, unsigned b) {
#if __has_builtin(__builtin_amdgcn_permlane32_swap)
    auto r = __builtin_amdgcn_permlane32_swap((int)a, (int)b, false, false);
    return make_uint2((unsigned)r[0], (unsigned)r[1]);
#else
    const int xa = (((int)threadIdx.x & 63) ^ 32) << 2;
    const unsigned pa = (unsigned)__builtin_amdgcn_ds_bpermute(xa, (int)a);
    const unsigned pb = (unsigned)__builtin_amdgcn_ds_bpermute(xa, (int)b);
    const bool hi = (threadIdx.x & 32) != 0;
    return make_uint2(hi ? pb : a, hi ? b : pa);
#endif
}

// lane^16 exchange (within each 32-lane half): ds_swizzle BitMode xor=16
static __device__ __forceinline__ unsigned swz16(unsigned v) {
    return (unsigned)__builtin_amdgcn_ds_swizzle((int)v, 0x401F);
}

// ---------------- P0: weights fp32 -> bf16 ----------------
__global__ __launch_bounds__(256) void wcvt_kernel(
    const float* __restrict__ Wq, const float* __restrict__ Wk, const float* __restrict__ Wv,
    unsigned short* __restrict__ wvb, unsigned short* __restrict__ wqb,
    unsigned short* __restrict__ wkb)
{
    int i = blockIdx.x * 256 + threadIdx.x;  // 0..20479
    if (i < 16384)      wvb[i]         = f2bf(Wv[i]);
    else if (i < 18432) wqb[i - 16384] = f2bf(Wq[i - 16384]);
    else                wkb[i - 18432] = f2bf(Wk[i - 18432]);
}

// ---------------- P1: fused transpose + projections (r8 config, best measured) ----
// Flat grid 512 blocks; b = blk & 7 pins each batch to one XCD. V written in
// flash's fragment-major layout: v3[b][jt=j>>6][s=(j>>4)&3][h=(j>>3)&1][c][e=j&7].
// Dense 16B V-stores via lane^16 ds_swizzle pairing (r7-verified).
__global__ __launch_bounds__(256) void proj_kernel(
    const float* __restrict__ x,
    const unsigned short* __restrict__ wvb, const unsigned short* __restrict__ wqb,
    const unsigned short* __restrict__ wkb,
    const float* __restrict__ bq, const float* __restrict__ bk, const float* __restrict__ bv,
    unsigned short* __restrict__ qb, unsigned short* __restrict__ kb,
    unsigned short* __restrict__ vt)
{
    __shared__ float lt[128][68];   // [c][n0..63], padded rows (16B-aligned stride)
    const int t = threadIdx.x;
    const int w = t >> 6, lane = t & 63;
    const int c16 = lane & 15, g16 = lane >> 4;
    const int b  = blockIdx.x & 7;
    const int n0 = (blockIdx.x >> 3) * 64;

    // stage x tile: 128 rows x 64 floats
    {
        const int n4 = t & 15;
#pragma unroll
        for (int pass = 0; pass < 8; ++pass) {
            const int c = (t >> 4) + 16 * pass;
            const float4 val = ((const float4*)(x + ((size_t)b * 128 + c) * NTOK + n0))[n4];
            *(float4*)&lt[c][n4 * 4] = val;
        }
    }
    __syncthreads();

    // xf fragments for this wave's 16 tokens (token = n0 + 16w + c16)
    const int nl = 16 * w + c16;
    s16x8 xf[4];
#pragma unroll
    for (int kc = 0; kc < 4; ++kc) {
        unsigned rr[8];
#pragma unroll
        for (int i = 0; i < 8; ++i) {
            const unsigned u = __float_as_uint(lt[32 * kc + 8 * g16 + i][nl]);
            rr[i] = u + 0x7FFFu + ((u >> 16) & 1u);
        }
        union { s16x8 v; unsigned u[4]; } cvt;
#pragma unroll
        for (int d = 0; d < 4; ++d)
            cvt.u[d] = __builtin_amdgcn_perm(rr[2 * d + 1], rr[2 * d], 0x07060302u);
        xf[kc] = cvt.v;
    }

    // ---- V = Wv * X  (fragment-major, dense 16B stores) ----
    unsigned short* vwp16 = vt + (size_t)b * (NTOK * 128) +
                            (size_t)(((n0 >> 6) * 8) + 2 * w + (g16 >> 1)) * 1024;
    const bool oddg = (g16 & 1) != 0;
#pragma unroll
    for (int mp = 0; mp < 4; ++mp) {
        f32x4 accA = {0.f, 0.f, 0.f, 0.f}, accB = {0.f, 0.f, 0.f, 0.f};
#pragma unroll
        for (int kc = 0; kc < 4; ++kc) {
            const s16x8 wfA = *(const s16x8*)(wvb + (size_t)(32 * mp      + c16) * 128 + 32 * kc + 8 * g16);
            const s16x8 wfB = *(const s16x8*)(wvb + (size_t)(32 * mp + 16 + c16) * 128 + 32 * kc + 8 * g16);
            accA = __builtin_amdgcn_mfma_f32_16x16x32_bf16(xf[kc], wfA, accA, 0, 0, 0);
            accB = __builtin_amdgcn_mfma_f32_16x16x32_bf16(xf[kc], wfB, accB, 0, 0, 0);
        }
        const float bvA = bv[32 * mp + c16], bvB = bv[32 * mp + 16 + c16];
        uint2 A, B;
        A.x = cvtpkbf(accA[0] + bvA, accA[1] + bvA);
        A.y = cvtpkbf(accA[2] + bvA, accA[3] + bvA);
        B.x = cvtpkbf(accB[0] + bvB, accB[1] + bvB);
        B.y = cvtpkbf(accB[2] + bvB, accB[3] + bvB);
        // exchange with lane^16: even lane keeps channel A row, odd keeps B row.
        const unsigned s0 = swz16(oddg ? A.x : B.x);
        const unsigned s1 = swz16(oddg ? A.y : B.y);
        uint4 W;
        W.x = oddg ? s0 : A.x;
        W.y = oddg ? s1 : A.y;
        W.z = oddg ? B.x : s0;
        W.w = oddg ? B.y : s1;
        const int crow = 32 * mp + (oddg ? 16 : 0) + c16;
        *(uint4*)(vwp16 + (size_t)crow * 8) = W;
    }
    // ---- Q, K ----
    f32x4 aq = {0.f, 0.f, 0.f, 0.f}, ak = {0.f, 0.f, 0.f, 0.f};
#pragma unroll
    for (int kc = 0; kc < 4; ++kc) {
        const s16x8 wqf = *(const s16x8*)(wqb + (size_t)c16 * 128 + 32 * kc + 8 * g16);
        const s16x8 wkf = *(const s16x8*)(wkb + (size_t)c16 * 128 + 32 * kc + 8 * g16);
        aq = __builtin_amdgcn_mfma_f32_16x16x32_bf16(wqf, xf[kc], aq, 0, 0, 0);
        ak = __builtin_amdgcn_mfma_f32_16x16x32_bf16(wkf, xf[kc], ak, 0, 0, 0);
    }
    const float4 bq4 = *(const float4*)(bq + 4 * g16);
    const float4 bk4 = *(const float4*)(bk + 4 * g16);
    const int n = n0 + 16 * w + c16;
    uint2 pq, pkk;
    pq.x  = cvtpkbf(QSCALE * (aq[0] + bq4.x), QSCALE * (aq[1] + bq4.y));
    pq.y  = cvtpkbf(QSCALE * (aq[2] + bq4.z), QSCALE * (aq[3] + bq4.w));
    pkk.x = cvtpkbf(ak[0] + bk4.x, ak[1] + bk4.y);
    pkk.y = cvtpkbf(ak[2] + bk4.z, ak[3] + bk4.w);
    *(uint2*)(qb + ((size_t)b * NTOK + n) * 16 + 4 * g16) = pq;
    *(uint2*)(kb + ((size_t)b * NTOK + n) * 16 + 4 * g16) = pkk;
}

// ---------------- P2: flash attention, Q-blocked (64 rows/wave), reg pipeline ----
// Grid 512 blocks (2/CU): b = blk & 7 (XCD-pinned batch), m-tile = blk>>3
// (64 q rows). 4 waves = (jw 0..1) x (cv 0..1): wave owns ALL 64 rows (two
// row-tiles rt), j-half jw, channel pair ct in {2cv,2cv+1}. No LDS/barriers
// in the loop.
//
// r13 lesson: scheduling (barriers, occupancy, prefetch, stagger) never moved
// the 67us pin because the chip-wide INTEGRALS are fixed by the tiling:
// V->register traffic (1MB V re-loaded per 32-row tile = 4MB/CU through the
// 64B/cyc L1 port = 27us) + VALU/trans (~26us/SIMD) sum to every measurement.
// Fix: Q-blocking. Each wave owns 64 rows and reuses every V fragment for TWO
// PV pairs -> V traffic halves (L1 port 13.5us); block's 4 (jw,cv) waves read
// disjoint V slices (no duplication). O doubles to 64 regs + A/B prefetch
// sets (~200 VGPR total) -> launch_bounds(256,2) (cap 256, spill impossible;
// r5 lesson). Hoisted zero C-operand (Z) kills per-tile sd zero-init movs.
// Verification: VGPR_Count must rise to ~180-210; WRITE_SIZE stays 16384 KB.
__global__ __launch_bounds__(256, 2) void flash_kernel(
    const unsigned short* __restrict__ qb, const unsigned short* __restrict__ kb,
    const unsigned short* __restrict__ vt, const float* __restrict__ x,
    const float* __restrict__ gamma, float* __restrict__ out)
{
    // cmb float[64][128] @0 (32768B); lb 4*64 floats @32768
    __shared__ __align__(16) unsigned char smem[33792];

    const int t = threadIdx.x;
    const int w = t >> 6, lane = t & 63;
    const int m31 = lane & 31, h = lane >> 5;
    const int cv = w & 1, jw = w >> 1;
    const int b  = blockIdx.x & 7;
    const int m0 = (blockIdx.x >> 3) * 64;

    // per-wave global bases (dense 1KB per wave-load)
    const unsigned short* vp = vt + (size_t)b * (NTOK * 128) +
                               (2 * jw) * 2048 + h * 1024 + (2 * cv) * 256 + m31 * 8;
    const unsigned short* kp = kb + (size_t)b * (NTOK * 16) +
                               (size_t)(32 * jw + m31) * 16 + 8 * h;

    // Q B-frags for both row-tiles; scale (incl. log2e) pre-folded into qb.
    const s16x8 qf0 = *(const s16x8*)(qb + ((size_t)b * NTOK + m0 + m31) * 16 + 8 * h);
    const s16x8 qf1 = *(const s16x8*)(qb + ((size_t)b * NTOK + m0 + 32 + m31) * 16 + 8 * h);

    // hoisted zero C-operand for the QK MFMAs (no per-tile v_mov zero-init)
    f32x16 Z;
#pragma unroll
    for (int r = 0; r < 16; ++r) Z[r] = 0.f;

    f32x16 O00, O01, O10, O11;   // O[rt][ci]: 64 loop-carried acc regs
#pragma unroll
    for (int r = 0; r < 16; ++r) { O00[r] = 0.f; O01[r] = 0.f; O10[r] = 0.f; O11[r] = 0.f; }
    float la0 = 0.f, la0b = 0.f, la1 = 0.f, la1b = 0.f;   // l partials per rt

    s16x8 kA, a00, a01, a10, a11;   // operand set A
    s16x8 kB, b00, b01, b10, b11;   // operand set B

#define LOADSET(K, V00, V01, V10, V11, jn) do {                       \
        const unsigned short* kpn_ = kp + (size_t)(jn) * 1024;        \
        const unsigned short* vpn_ = vp + (size_t)(jn) * 8192;        \
        K   = *(const s16x8*)kpn_;                                    \
        V00 = *(const s16x8*)(vpn_);                                  \
        V01 = *(const s16x8*)(vpn_ + 256);                            \
        V10 = *(const s16x8*)(vpn_ + 2048);                           \
        V11 = *(const s16x8*)(vpn_ + 2304);                           \
    } while (0)

    // one row-tile's softmax: sd -> exp2 -> pack -> pf pair (r2-verified chain)
#define SOFTMAX1(K, QF, LA, LAB, PF0, PF1) do {                                     \
        f32x16 sd_ = __builtin_amdgcn_mfma_f32_32x32x16_bf16(K, QF, Z, 0, 0, 0);    \
        uint2 pk_[4];                                                               \
        _Pragma("unroll") for (int q_ = 0; q_ < 4; ++q_) {                          \
            const float e0_ = EXP2F(sd_[4 * q_ + 0]);                               \
            const float e1_ = EXP2F(sd_[4 * q_ + 1]);                               \
            const float e2_ = EXP2F(sd_[4 * q_ + 2]);                               \
            const float e3_ = EXP2F(sd_[4 * q_ + 3]);                               \
            LA += e0_ + e2_; LAB += e1_ + e3_;                                      \
            pk_[q_].x = cvtpkbf(e0_, e1_);                                          \
            pk_[q_].y = cvtpkbf(e2_, e3_);                                          \
        }                                                                           \
        {                                                                           \
            const uint2 rx_ = plswap32(pk_[0].x, pk_[1].x);                         \
            const uint2 ry_ = plswap32(pk_[0].y, pk_[1].y);                         \
            union { s16x8 v; unsigned u[4]; } U_;                                   \
            U_.u[0] = rx_.x; U_.u[1] = ry_.x; U_.u[2] = rx_.y; U_.u[3] = ry_.y;     \
            PF0 = U_.v;                                                             \
        }                                                                           \
        {                                                                           \
            const uint2 rx_ = plswap32(pk_[2].x, pk_[3].x);                         \
            const uint2 ry_ = plswap32(pk_[2].y, pk_[3].y);                         \
            union { s16x8 v; unsigned u[4]; } U_;                                   \
            U_.u[0] = rx_.x; U_.u[1] = ry_.x; U_.u[2] = rx_.y; U_.u[3] = ry_.y;     \
            PF1 = U_.v;                                                             \
        }                                                                           \
    } while (0)

#define COMPUTE(K, V00, V01, V10, V11) do {                                         \
        s16x8 pf00_, pf01_, pf10_, pf11_;                                           \
        SOFTMAX1(K, qf0, la0, la0b, pf00_, pf01_);                                  \
        SOFTMAX1(K, qf1, la1, la1b, pf10_, pf11_);                                  \
        O00 = __builtin_amdgcn_mfma_f32_32x32x16_bf16(V00, pf00_, O00, 0, 0, 0);    \
        O01 = __builtin_amdgcn_mfma_f32_32x32x16_bf16(V01, pf00_, O01, 0, 0, 0);    \
        O00 = __builtin_amdgcn_mfma_f32_32x32x16_bf16(V10, pf01_, O00, 0, 0, 0);    \
        O01 = __builtin_amdgcn_mfma_f32_32x32x16_bf16(V11, pf01_, O01, 0, 0, 0);    \
        O10 = __builtin_amdgcn_mfma_f32_32x32x16_bf16(V00, pf10_, O10, 0, 0, 0);    \
        O11 = __builtin_amdgcn_mfma_f32_32x32x16_bf16(V01, pf10_, O11, 0, 0, 0);    \
        O10 = __builtin_amdgcn_mfma_f32_32x32x16_bf16(V10, pf11_, O10, 0, 0, 0);    \
        O11 = __builtin_amdgcn_mfma_f32_32x32x16_bf16(V11, pf11_, O11, 0, 0, 0);    \
    } while (0)

    LOADSET(kA, a00, a01, a10, a11, 0);
    LOADSET(kB, b00, b01, b10, b11, 1);

#pragma unroll 1
    for (int jt = 0; jt < 64; jt += 2) {
        COMPUTE(kA, a00, a01, a10, a11);
        LOADSET(kA, a00, a01, a10, a11, jt + 2 < 64 ? jt + 2 : 63);
        __builtin_amdgcn_sched_barrier(0);   // pin A-loads above B-compute
        COMPUTE(kB, b00, b01, b10, b11);
        LOADSET(kB, b00, b01, b10, b11, jt + 3 < 64 ? jt + 3 : 63);
        __builtin_amdgcn_sched_barrier(0);   // pin B-loads above next A-compute
    }
#undef LOADSET
#undef SOFTMAX1
#undef COMPUTE

    // own-half l per row-tile (h-lanes hold disjoint j subsets of the half)
    float l0 = la0 + la0b;  l0 += __shfl_xor(l0, 32);
    float l1 = la1 + la1b;  l1 += __shfl_xor(l1, 32);

    float* cmb = (float*)smem;             // [64][128] floats
    float* lb  = (float*)(smem + 32768);   // [4][64]
    if (lane < 32) { lb[w * 64 + m31] = l0; lb[w * 64 + 32 + m31] = l1; }
    // jw partner is w^2 (same cv). cv partners duplicate softmax -> same l.
    if (jw == 1) {
#pragma unroll
        for (int r = 0; r < 16; ++r) {
            cmb[((0 * 2 + 0) * 16 + r) * 128 + cv * 64 + lane] = O00[r];
            cmb[((0 * 2 + 1) * 16 + r) * 128 + cv * 64 + lane] = O01[r];
            cmb[((1 * 2 + 0) * 16 + r) * 128 + cv * 64 + lane] = O10[r];
            cmb[((1 * 2 + 1) * 16 + r) * 128 + cv * 64 + lane] = O11[r];
        }
    }
    __syncthreads();
    const float lt0 = l0 + lb[(w ^ 2) * 64 + m31];
    const float lt1 = l1 + lb[(w ^ 2) * 64 + 32 + m31];

    if (jw == 0) {
        const float linv0 = 1.f / lt0;
        const float linv1 = 1.f / lt1;
        const float g = gamma[0];
#pragma unroll
        for (int rt = 0; rt < 2; ++rt)
#pragma unroll
            for (int ci = 0; ci < 2; ++ci) {
                const int ct = 2 * cv + ci;
                const float linv = rt ? linv1 : linv0;
#pragma unroll
                for (int r = 0; r < 16; ++r) {
                    float ov = (rt ? (ci ? O11[r] : O10[r]) : (ci ? O01[r] : O00[r]));
                    ov += cmb[((rt * 2 + ci) * 16 + r) * 128 + cv * 64 + lane];
                    const int c = 32 * ct + (r & 3) + 8 * (r >> 2) + 4 * h;
                    const size_t idx = ((size_t)b * 128 + c) * NTOK + m0 + rt * 32 + m31;
                    out[idx] = fmaf(g, ov * linv, x[idx]);
                }
            }
    }
}

extern "C" void kernel_launch(void* const* d_in, const int* in_sizes, int n_in,
                              void* d_out, int out_size, void* d_ws, size_t ws_size,
                              hipStream_t stream)
{
    const float* x     = (const float*)d_in[0];
    const float* Wq    = (const float*)d_in[1];
    const float* bq    = (const float*)d_in[2];
    const float* Wk    = (const float*)d_in[3];
    const float* bk    = (const float*)d_in[4];
    const float* Wv    = (const float*)d_in[5];
    const float* bv    = (const float*)d_in[6];
    const float* gamma = (const float*)d_in[7];
    float* out = (float*)d_out;

    // workspace (bf16 elements)
    unsigned short* qb  = (unsigned short*)d_ws;                 // 8*4096*16
    unsigned short* kb  = qb  + (size_t)NB_ * NTOK * 16;
    unsigned short* vt  = kb  + (size_t)NB_ * NTOK * 16;         // 8*128*4096 (fragment-major)
    unsigned short* wvb = vt  + (size_t)NB_ * 128 * NTOK;        // 128*128
    unsigned short* wqb = wvb + 16384;                           // 16*128
    unsigned short* wkb = wqb + 2048;

    wcvt_kernel<<<80, 256, 0, stream>>>(Wq, Wk, Wv, wvb, wqb, wkb);
    proj_kernel<<<512, 256, 0, stream>>>(x, wvb, wqb, wkb, bq, bk, bv, qb, kb, vt);
    flash_kernel<<<512, 256, 0, stream>>>(qb, kb, vt, x, gamma, out);
}